// Round 4
// baseline (369.589 us; speedup 1.0000x reference)
//
#include <hip/hip_runtime.h>
#include <hip/hip_cooperative_groups.h>

namespace cg = cooperative_groups;

// Problem constants: B=2048, D=2048, H=16, Q=128, N=8192, V=128
// Identity: softmax rows sum to 1 => attn_rowsum == 1, so
//   out[b,:] = x[b,:] + c,  c[d] = dot(vmean, WoF[d,:]),
//   WoF[d,v] = sum_h Wo[d, h*128+v],  vmean = mean_n values[n,:].
// Single cooperative kernel, 3 phases with 2 grid syncs:
//   A: values colsum partials (128 blks) + WoF head-fold (896 blks)  [20 MB]
//   B: vmean reduce + c[d] (128 blks, each d computed ONCE)          [~1 MB L2]
//   C: out = x + c streamed by all blocks                            [32 MB]

#define NROWS 8192
#define VDIM  128
#define DDIM  2048
#define BDIM  2048
#define GRID  1024
#define PBLK  128

__global__ void __launch_bounds__(256) fused_kernel(
    const float4* __restrict__ vals4,
    const float4* __restrict__ Wo4,
    const float4* __restrict__ x4,
    float4* __restrict__ out4,
    float4* __restrict__ partial4,   // [128][32] f4
    float4* __restrict__ WoF4,       // [2048][32] f4
    float*  __restrict__ cvec)       // [2048]
{
    cg::grid_group grid = cg::this_grid();
    __shared__ float4 s[256];
    __shared__ float4 vm_lds[32];
    const int t = threadIdx.x;
    const int bid = blockIdx.x;

    // ---------------- Phase A ----------------
    if (bid < PBLK) {
        // values colsum: rows [bid*64, +64) = 2048 f4; col-quad (t&31) invariant
        float4 acc = make_float4(0.f, 0.f, 0.f, 0.f);
        const int base = bid * 2048;
#pragma unroll
        for (int j = 0; j < 8; ++j) {
            float4 v = vals4[base + t + 256 * j];
            acc.x += v.x; acc.y += v.y; acc.z += v.z; acc.w += v.w;
        }
        s[t] = acc;
        __syncthreads();
        if (t < 32) {
            float4 r = s[t];
#pragma unroll
            for (int k = 1; k < 8; ++k) {
                float4 v = s[t + 32 * k];
                r.x += v.x; r.y += v.y; r.z += v.z; r.w += v.w;
            }
            partial4[bid * 32 + t] = r;
        }
    } else {
        // WoF fold: rows d = wb, wb+896, wb+1792 (<2048)
        const int wb = bid - PBLK;   // 0..895
        const int vq = t & 31;
        const int hg = t >> 5;       // handles h = 2*hg, 2*hg+1
        for (int d = wb; d < DDIM; d += GRID - PBLK) {
            const float4* row = Wo4 + (size_t)d * 512;
            float4 a = row[(2 * hg) * 32 + vq];
            float4 b = row[(2 * hg + 1) * 32 + vq];
            a.x += b.x; a.y += b.y; a.z += b.z; a.w += b.w;
            s[t] = a;
            __syncthreads();
            if (t < 32) {
                float4 r = s[t];
#pragma unroll
                for (int k = 1; k < 8; ++k) {
                    float4 v = s[t + 32 * k];
                    r.x += v.x; r.y += v.y; r.z += v.z; r.w += v.w;
                }
                WoF4[d * 32 + t] = r;
            }
            __syncthreads();
        }
    }
    __threadfence();
    grid.sync();

    // ---------------- Phase B ----------------
    if (bid < PBLK) {
        // vmean reduce: partial [128][32] f4 = 4096 f4 (L2-resident, 64 KB)
        float4 acc = make_float4(0.f, 0.f, 0.f, 0.f);
#pragma unroll
        for (int j = 0; j < 16; ++j) {
            float4 v = partial4[t + 256 * j];
            acc.x += v.x; acc.y += v.y; acc.z += v.z; acc.w += v.w;
        }
        s[t] = acc;
        __syncthreads();
        if (t < 32) {
            float4 r = s[t];
#pragma unroll
            for (int k = 1; k < 8; ++k) {
                float4 v = s[t + 32 * k];
                r.x += v.x; r.y += v.y; r.z += v.z; r.w += v.w;
            }
            const float inv = 1.0f / (float)NROWS;
            r.x *= inv; r.y *= inv; r.z *= inv; r.w *= inv;
            vm_lds[t] = r;
        }
        __syncthreads();
        // c for 16 d's: 16 threads per d, 2 f4 each, shfl-tree reduce
        const int dl = t >> 4;       // 0..15
        const int part = t & 15;
        const int d = bid * 16 + dl;
        float4 w0 = WoF4[d * 32 + part * 2];
        float4 w1 = WoF4[d * 32 + part * 2 + 1];
        float4 v0 = vm_lds[part * 2];
        float4 v1 = vm_lds[part * 2 + 1];
        float dot = w0.x * v0.x + w0.y * v0.y + w0.z * v0.z + w0.w * v0.w
                  + w1.x * v1.x + w1.y * v1.y + w1.z * v1.z + w1.w * v1.w;
#pragma unroll
        for (int off = 8; off; off >>= 1) dot += __shfl_xor(dot, off);
        if (part == 0) cvec[d] = dot;
    }
    __threadfence();
    grid.sync();

    // ---------------- Phase C ----------------
    // out = x + c; flat f4 index i = bid*1024 + j*256 + t; col-quad = i & 511.
    const float4* __restrict__ c4 = (const float4*)cvec;
    const float4 cA = c4[t];         // j even: (j*256+t) & 511 == t
    const float4 cB = c4[t + 256];   // j odd
    const size_t base = (size_t)bid * 1024 + t;
#pragma unroll
    for (int j = 0; j < 4; ++j) {
        const size_t i = base + (size_t)j * 256;
        float4 xv = x4[i];
        const float4 cv = (j & 1) ? cB : cA;
        xv.x += cv.x; xv.y += cv.y; xv.z += cv.z; xv.w += cv.w;
        out4[i] = xv;
    }
}

// ---------------------------------------------------------------------------
// Fallback (non-cooperative 3-dispatch path) in case cooperative launch
// is rejected at runtime. Same math.
__global__ void fb_col_partial(const float4* __restrict__ vals4,
                               float4* __restrict__ partial4) {
    __shared__ float4 s[256];
    const int t = threadIdx.x, b = blockIdx.x;
    float4 acc = make_float4(0.f, 0.f, 0.f, 0.f);
    const int base = b * 2048;
#pragma unroll
    for (int j = 0; j < 8; ++j) {
        float4 v = vals4[base + t + 256 * j];
        acc.x += v.x; acc.y += v.y; acc.z += v.z; acc.w += v.w;
    }
    s[t] = acc;
    __syncthreads();
    if (t < 32) {
        float4 r = s[t];
#pragma unroll
        for (int k = 1; k < 8; ++k) {
            float4 v = s[t + 32 * k];
            r.x += v.x; r.y += v.y; r.z += v.z; r.w += v.w;
        }
        partial4[b * 32 + t] = r;
    }
}

__global__ void fb_compute_c(const float* __restrict__ partial,
                             const float4* __restrict__ Wo4,
                             float* __restrict__ cvec) {
    __shared__ float4 s[256];
    __shared__ float4 vm_lds[32];
    const int t = threadIdx.x;
    const float4* __restrict__ p4 = (const float4*)partial;
    float4 acc = make_float4(0.f, 0.f, 0.f, 0.f);
#pragma unroll
    for (int j = 0; j < 16; ++j) {
        float4 v = p4[t + 256 * j];
        acc.x += v.x; acc.y += v.y; acc.z += v.z; acc.w += v.w;
    }
    s[t] = acc;
    __syncthreads();
    if (t < 32) {
        float4 r = s[t];
#pragma unroll
        for (int k = 1; k < 8; ++k) {
            float4 v = s[t + 32 * k];
            r.x += v.x; r.y += v.y; r.z += v.z; r.w += v.w;
        }
        const float inv = 1.0f / (float)NROWS;
        r.x *= inv; r.y *= inv; r.z *= inv; r.w *= inv;
        vm_lds[t] = r;
    }
    __syncthreads();
    const int lane = t & 63, wave = t >> 6;
    const int d = blockIdx.x * 4 + wave;
    const float4 vm = vm_lds[lane & 31];
    const float4* row = Wo4 + (size_t)d * 512;
    float dot = 0.f;
#pragma unroll
    for (int i = 0; i < 8; ++i) {
        float4 w = row[i * 64 + lane];
        dot += w.x * vm.x + w.y * vm.y + w.z * vm.z + w.w * vm.w;
    }
#pragma unroll
    for (int off = 32; off; off >>= 1) dot += __shfl_down(dot, off);
    if (lane == 0) cvec[d] = dot;
}

__global__ void fb_add_bias(const float4* __restrict__ x4,
                            const float* __restrict__ cvec,
                            float4* __restrict__ out4) {
    const float4* __restrict__ c4 = (const float4*)cvec;
    const int n4 = (BDIM * DDIM) / 4;
    int idx = blockIdx.x * blockDim.x + threadIdx.x;
    const int stride = gridDim.x * blockDim.x;
    for (int i = idx; i < n4; i += stride) {
        float4 xv = x4[i];
        float4 cv = c4[i & 511];
        xv.x += cv.x; xv.y += cv.y; xv.z += cv.z; xv.w += cv.w;
        out4[i] = xv;
    }
}

// ---------------------------------------------------------------------------
extern "C" void kernel_launch(void* const* d_in, const int* in_sizes, int n_in,
                              void* d_out, int out_size, void* d_ws, size_t ws_size,
                              hipStream_t stream) {
    // inputs: 0=x [B,D], 1=keys (unused), 2=values [N,V], 3=Wq (unused), 4=Wo [D,H*V]
    const float* x      = (const float*)d_in[0];
    const float* values = (const float*)d_in[2];
    const float* Wo     = (const float*)d_in[4];
    float* out = (float*)d_out;
    float* ws  = (float*)d_ws;

    const float4* vals4 = (const float4*)values;
    const float4* Wo4   = (const float4*)Wo;
    const float4* x4    = (const float4*)x;
    float4* out4 = (float4*)out;
    float4* partial4 = (float4*)ws;                     // 128*32 f4 = 64 KB
    float4* WoF4     = (float4*)(ws + 16384);           // 2048*32 f4 = 1 MB
    float*  cvec     = ws + 16384 + 262144;             // 2048 floats

    void* args[] = {(void*)&vals4, (void*)&Wo4, (void*)&x4, (void*)&out4,
                    (void*)&partial4, (void*)&WoF4, (void*)&cvec};
    hipError_t err = hipLaunchCooperativeKernel((const void*)fused_kernel,
                                                dim3(GRID), dim3(256),
                                                args, 0, stream);
    if (err != hipSuccess) {
        // non-cooperative fallback: 3 dispatches, same math
        fb_col_partial<<<128, 256, 0, stream>>>(vals4, partial4);
        fb_compute_c<<<512, 256, 0, stream>>>((const float*)partial4, Wo4, cvec);
        fb_add_bias<<<1024, 256, 0, stream>>>(x4, cvec, out4);
    }
}

// Round 5
// 20.560 us; speedup vs baseline: 17.9757x; 17.9757x over previous
//
#include <hip/hip_runtime.h>

// Problem constants: B=2048, D=2048, H=16, Q=128, N=8192, V=128
// Identity: softmax rows sum to 1 => attn_rowsum == 1, so
//   out[b,:] = x[b,:] + c,  c[d] = dot(vmean, WoF[d,:]),
//   WoF[d,v] = sum_h Wo[d, h*128+v],  vmean = mean_n values[n,:].
// 3 width-matched dispatches (NO grid.sync — costs ~170us/sync on 8-XCD):
//   K1 (1024 blks): 256 values-colsum partials + 768 WoF head-fold   [20 MB]
//   K2 (32 blks):   vmean reduce + c[d], each d exactly once         [L2 only]
//   K3 (2048 blks): out = x + c, one row per block                   [32 MB]

#define NROWS 8192
#define VDIM  128
#define DDIM  2048
#define BDIM  2048
#define VBLK  256        // K1 blocks doing values (32 rows each)
#define WBLK  768        // K1 blocks doing WoF fold

// ---------------------------------------------------------------------------
// K1: fused values-colsum partials + Wo head-fold. 1024 blocks.
__global__ void __launch_bounds__(256) prep_kernel(
    const float4* __restrict__ vals4,
    const float4* __restrict__ Wo4,
    float4* __restrict__ partial4,   // [256][32] f4
    float4* __restrict__ WoF4)       // [2048][32] f4
{
    __shared__ float4 s[256];
    const int t = threadIdx.x;
    const int bid = blockIdx.x;

    if (bid < VBLK) {
        // values rows [bid*32, +32) = 1024 f4; col-quad (t&31) invariant
        float4 acc = make_float4(0.f, 0.f, 0.f, 0.f);
        const int base = bid * 1024;
#pragma unroll
        for (int j = 0; j < 4; ++j) {
            float4 v = vals4[base + t + 256 * j];
            acc.x += v.x; acc.y += v.y; acc.z += v.z; acc.w += v.w;
        }
        s[t] = acc;
        __syncthreads();
        if (t < 32) {
            float4 r = s[t];
#pragma unroll
            for (int k = 1; k < 8; ++k) {
                float4 v = s[t + 32 * k];
                r.x += v.x; r.y += v.y; r.z += v.z; r.w += v.w;
            }
            partial4[bid * 32 + t] = r;
        }
    } else {
        // WoF fold: d = wb, wb+768, wb+1536 (<2048)
        const int wb = bid - VBLK;   // 0..767
        const int vq = t & 31;       // v quad
        const int hg = t >> 5;       // 0..7: handles h = 2*hg, 2*hg+1
        for (int d = wb; d < DDIM; d += WBLK) {
            const float4* row = Wo4 + (size_t)d * 512;
            float4 a = row[(2 * hg) * 32 + vq];
            float4 b = row[(2 * hg + 1) * 32 + vq];
            a.x += b.x; a.y += b.y; a.z += b.z; a.w += b.w;
            s[t] = a;
            __syncthreads();
            if (t < 32) {
                float4 r = s[t];
#pragma unroll
                for (int k = 1; k < 8; ++k) {
                    float4 v = s[t + 32 * k];
                    r.x += v.x; r.y += v.y; r.z += v.z; r.w += v.w;
                }
                WoF4[d * 32 + t] = r;
            }
            __syncthreads();
        }
    }
}

// ---------------------------------------------------------------------------
// K2: vmean reduce + c[d]. 32 blocks x 256 threads; block handles 64 d's.
__global__ void __launch_bounds__(256) c_kernel(
    const float4* __restrict__ partial4,  // [256][32] f4 (128 KB, L2)
    const float4* __restrict__ WoF4,      // [2048][32] f4 (1 MB, L2)
    float* __restrict__ cvec)             // [2048]
{
    __shared__ float4 s[256];
    __shared__ float4 vm_lds[32];
    const int t = threadIdx.x;

    // vmean: 8192 f4, 32 per thread; col-quad (t&31) invariant
    float4 acc = make_float4(0.f, 0.f, 0.f, 0.f);
#pragma unroll
    for (int j = 0; j < 32; ++j) {
        float4 v = partial4[t + 256 * j];
        acc.x += v.x; acc.y += v.y; acc.z += v.z; acc.w += v.w;
    }
    s[t] = acc;
    __syncthreads();
    if (t < 32) {
        float4 r = s[t];
#pragma unroll
        for (int k = 1; k < 8; ++k) {
            float4 v = s[t + 32 * k];
            r.x += v.x; r.y += v.y; r.z += v.z; r.w += v.w;
        }
        const float inv = 1.0f / (float)NROWS;
        r.x *= inv; r.y *= inv; r.z *= inv; r.w *= inv;
        vm_lds[t] = r;
    }
    __syncthreads();

    // c: 4 threads per d, 8 f4 each
    const int dl = t >> 2;           // 0..63
    const int part = t & 3;
    const int d = blockIdx.x * 64 + dl;
    float dot = 0.f;
#pragma unroll
    for (int j = 0; j < 8; ++j) {
        float4 w = WoF4[(size_t)d * 32 + part * 8 + j];
        float4 vm = vm_lds[part * 8 + j];
        dot += w.x * vm.x + w.y * vm.y + w.z * vm.z + w.w * vm.w;
    }
    dot += __shfl_xor(dot, 1);
    dot += __shfl_xor(dot, 2);
    if (part == 0) cvec[d] = dot;
}

// ---------------------------------------------------------------------------
// K3: out[b,d] = x[b,d] + c[d]. 2048 blocks, one row each, f4-vectorized.
__global__ void __launch_bounds__(256) add_kernel(
    const float4* __restrict__ x4,
    const float* __restrict__ cvec,
    float4* __restrict__ out4)
{
    const float4* __restrict__ c4 = (const float4*)cvec;
    const int t = threadIdx.x;
    const size_t base = (size_t)blockIdx.x * 512 + t;
    float4 xv0 = x4[base];
    float4 xv1 = x4[base + 256];
    float4 cv0 = c4[t];
    float4 cv1 = c4[t + 256];
    xv0.x += cv0.x; xv0.y += cv0.y; xv0.z += cv0.z; xv0.w += cv0.w;
    xv1.x += cv1.x; xv1.y += cv1.y; xv1.z += cv1.z; xv1.w += cv1.w;
    out4[base] = xv0;
    out4[base + 256] = xv1;
}

// ---------------------------------------------------------------------------
extern "C" void kernel_launch(void* const* d_in, const int* in_sizes, int n_in,
                              void* d_out, int out_size, void* d_ws, size_t ws_size,
                              hipStream_t stream) {
    // inputs: 0=x [B,D], 1=keys (unused), 2=values [N,V], 3=Wq (unused), 4=Wo [D,H*V]
    const float* x      = (const float*)d_in[0];
    const float* values = (const float*)d_in[2];
    const float* Wo     = (const float*)d_in[4];
    float* out = (float*)d_out;
    float* ws  = (float*)d_ws;

    float4* partial4 = (float4*)ws;                       // 256*32 f4 = 128 KB
    float4* WoF4     = (float4*)(ws + 32768);             // 2048*32 f4 = 1 MB
    float*  cvec     = ws + 32768 + 262144;               // 2048 floats

    prep_kernel<<<VBLK + WBLK, 256, 0, stream>>>((const float4*)values,
                                                 (const float4*)Wo,
                                                 partial4, WoF4);
    c_kernel<<<32, 256, 0, stream>>>(partial4, WoF4, cvec);
    add_kernel<<<2048, 256, 0, stream>>>((const float4*)x, cvec, (float4*)out);
}

// Round 7
// 20.025 us; speedup vs baseline: 18.4567x; 1.0268x over previous
//
#include <hip/hip_runtime.h>

// Problem constants: B=2048, D=2048, H=16, Q=128, N=8192, V=128
// Identity: softmax rows sum to 1 => attn_rowsum == 1, so
//   out[b,:] = x[b,:] + c,  c[d] = sum_k vmean[k & 127] * Wo[d, k],
//   vmean = mean_n values[n,:].
// 3 dispatches, no WoF intermediate (Wo read exactly once, in D2):
//   D1 (64 blks):   values colsum -> partial[64][128]          [4 MB HBM]
//   D2 (512 blks):  Wo rows preloaded to regs (overlaps the 32 KB L2-resident
//                   vmean prologue), c[d] for 4 d's per block  [16 MB HBM]
//   D3 (2048 blks): out = x + c, one row per block             [32 MB HBM]
// NO grid-wide sync of any kind (R4: grid.sync ~170us; R6: manual barrier
// diverges under graph replay).

#define NROWS 8192
#define VDIM  128
#define DDIM  2048
#define BDIM  2048

// ---------------------------------------------------------------------------
// D1: values colsum partials. 64 blocks x 256 threads; block reads 128 rows
// (4096 f4), thread sums 16 f4 at stride 256 (col-quad t&31 invariant).
__global__ void __launch_bounds__(256) colsum_kernel(
    const float4* __restrict__ vals4,
    float4* __restrict__ partial4)   // [64][32] f4
{
    __shared__ float4 s[256];
    const int t = threadIdx.x;
    const int bid = blockIdx.x;
    float4 acc = make_float4(0.f, 0.f, 0.f, 0.f);
    const int base = bid * 4096;
#pragma unroll
    for (int j = 0; j < 16; ++j) {
        float4 v = vals4[base + t + 256 * j];
        acc.x += v.x; acc.y += v.y; acc.z += v.z; acc.w += v.w;
    }
    s[t] = acc;
    __syncthreads();
    if (t < 32) {
        float4 r = s[t];
#pragma unroll
        for (int k = 1; k < 8; ++k) {
            float4 v = s[t + 32 * k];
            r.x += v.x; r.y += v.y; r.z += v.z; r.w += v.w;
        }
        partial4[bid * 32 + t] = r;
    }
}

// ---------------------------------------------------------------------------
// D2: c[d] for d = bid*4 .. +4, directly from Wo.
// Preload 4 Wo rows (2 f4/thread/row) into registers FIRST so the 32 KB
// HBM read overlaps the L2-resident vmean reduce. Both f4s of a row share
// the same vmean quad (t&31), so dot = (w0+w1). vm.
__global__ void __launch_bounds__(256) c_kernel(
    const float4* __restrict__ partial4,  // [64][32] f4 (32 KB, L2)
    const float4* __restrict__ Wo4,
    float4* __restrict__ cvec4)           // [512] f4 = c[2048]
{
    __shared__ float4 s[256];
    __shared__ float4 vm_lds[32];
    const int t = threadIdx.x;
    const int d0 = blockIdx.x * 4;

    // issue Wo loads first (32 KB -> registers)
    float4 w[4][2];
#pragma unroll
    for (int r = 0; r < 4; ++r) {
        const float4* row = Wo4 + (size_t)(d0 + r) * 512;
        w[r][0] = row[t];
        w[r][1] = row[t + 256];
    }

    // vmean: partial 64x32 f4 = 2048 f4; 8 per thread; quad (t&31) invariant
    float4 acc = make_float4(0.f, 0.f, 0.f, 0.f);
#pragma unroll
    for (int j = 0; j < 8; ++j) {
        float4 v = partial4[t + 256 * j];
        acc.x += v.x; acc.y += v.y; acc.z += v.z; acc.w += v.w;
    }
    s[t] = acc;
    __syncthreads();
    if (t < 32) {
        float4 r = s[t];
#pragma unroll
        for (int k = 1; k < 8; ++k) {
            float4 v = s[t + 32 * k];
            r.x += v.x; r.y += v.y; r.z += v.z; r.w += v.w;
        }
        const float inv = 1.0f / (float)NROWS;
        r.x *= inv; r.y *= inv; r.z *= inv; r.w *= inv;
        vm_lds[t] = r;
    }
    __syncthreads();

    // per-thread dots for the 4 rows
    const float4 vm = vm_lds[t & 31];
    float4 dots;
    {
        float* dp = (float*)&dots;
#pragma unroll
        for (int r = 0; r < 4; ++r) {
            float4 a = w[r][0], b = w[r][1];
            a.x += b.x; a.y += b.y; a.z += b.z; a.w += b.w;
            dp[r] = a.x * vm.x + a.y * vm.y + a.z * vm.z + a.w * vm.w;
        }
    }
    s[t] = dots;
    __syncthreads();

    // reduce 256 partial dots -> 1 float4 (4 c values)
    if (t < 64) {
        float4 r = s[t];
#pragma unroll
        for (int k = 1; k < 4; ++k) {
            float4 v = s[t + 64 * k];
            r.x += v.x; r.y += v.y; r.z += v.z; r.w += v.w;
        }
#pragma unroll
        for (int off = 32; off; off >>= 1) {
            r.x += __shfl_down(r.x, off);
            r.y += __shfl_down(r.y, off);
            r.z += __shfl_down(r.z, off);
            r.w += __shfl_down(r.w, off);
        }
        if (t == 0) cvec4[blockIdx.x] = r;
    }
}

// ---------------------------------------------------------------------------
// D3: out[b,d] = x[b,d] + c[d]. 2048 blocks, one row each (proven R5 kernel).
__global__ void __launch_bounds__(256) add_kernel(
    const float4* __restrict__ x4,
    const float* __restrict__ cvec,
    float4* __restrict__ out4)
{
    const float4* __restrict__ c4 = (const float4*)cvec;
    const int t = threadIdx.x;
    const size_t base = (size_t)blockIdx.x * 512 + t;
    float4 xv0 = x4[base];
    float4 xv1 = x4[base + 256];
    float4 cv0 = c4[t];
    float4 cv1 = c4[t + 256];
    xv0.x += cv0.x; xv0.y += cv0.y; xv0.z += cv0.z; xv0.w += cv0.w;
    xv1.x += cv1.x; xv1.y += cv1.y; xv1.z += cv1.z; xv1.w += cv1.w;
    out4[base] = xv0;
    out4[base + 256] = xv1;
}

// ---------------------------------------------------------------------------
extern "C" void kernel_launch(void* const* d_in, const int* in_sizes, int n_in,
                              void* d_out, int out_size, void* d_ws, size_t ws_size,
                              hipStream_t stream) {
    // inputs: 0=x [B,D], 1=keys (unused), 2=values [N,V], 3=Wq (unused), 4=Wo [D,H*V]
    const float4* vals4 = (const float4*)d_in[2];
    const float4* Wo4   = (const float4*)d_in[4];
    const float4* x4    = (const float4*)d_in[0];
    float4* out4 = (float4*)d_out;
    char* ws = (char*)d_ws;

    float4* partial4 = (float4*)ws;               // 64*32 f4 = 32 KB
    float4* cvec4    = (float4*)(ws + 32768);     // 512 f4 = 8 KB

    colsum_kernel<<<64, 256, 0, stream>>>(vals4, partial4);
    c_kernel<<<512, 256, 0, stream>>>(partial4, Wo4, cvec4);
    add_kernel<<<2048, 256, 0, stream>>>(x4, (const float*)cvec4, out4);
}